// Round 3
// baseline (78.748 us; speedup 1.0000x reference)
//
#include <hip/hip_runtime.h>
#include <math.h>

#define A_TOT   18675      // 83*25*9
#define N_PRE   12000
#define N_POST  2000
#define IMG_X   1333.0f
#define IMG_Y   402.0f
#define MIN_SZ  16.0f
#define NMS_T   0.7f
#define NBUCK   65536

// ---------------- K1: decode -> roi, key64, bucket histogram -----------------
__global__ void decode_kernel(const float* __restrict__ anch,
                              const float* __restrict__ cls,
                              const float* __restrict__ pred,
                              float4* __restrict__ roi,
                              unsigned long long* __restrict__ key,
                              unsigned* __restrict__ hist) {
    int i = blockIdx.x * blockDim.x + threadIdx.x;
    if (i >= A_TOT) return;

    float ax1 = anch[4*i+0], ay1 = anch[4*i+1], ax2 = anch[4*i+2], ay2 = anch[4*i+3];
    float h_a  = __fsub_rn(ay2, ay1);
    float w_a  = __fsub_rn(ax2, ax1);
    float cy_a = __fadd_rn(ay1, __fmul_rn(0.5f, h_a));
    float cx_a = __fadd_rn(ax1, __fmul_rn(0.5f, w_a));

    float dx = pred[4*i+0], dy = pred[4*i+1], dw = pred[4*i+2], dh = pred[4*i+3];

    float cy = __fadd_rn(__fmul_rn(dy, h_a), cy_a);
    float cx = __fadd_rn(__fmul_rn(dx, w_a), cx_a);
    float h  = __fmul_rn(expf(dh), h_a);
    float w  = __fmul_rn(expf(dw), w_a);

    float hw = __fmul_rn(0.5f, w);
    float hh = __fmul_rn(0.5f, h);
    float x1 = fminf(fmaxf(__fsub_rn(cx, hw), 0.0f), IMG_X);
    float x2 = fminf(fmaxf(__fadd_rn(cx, hw), 0.0f), IMG_X);
    float y1 = fminf(fmaxf(__fsub_rn(cy, hh), 0.0f), IMG_Y);
    float y2 = fminf(fmaxf(__fadd_rn(cy, hh), 0.0f), IMG_Y);

    bool valid = (__fsub_rn(y2, y1) >= MIN_SZ) && (__fsub_rn(x2, x1) >= MIN_SZ);

    roi[i] = make_float4(x1, y1, x2, y2);

    float s = valid ? cls[2*i+1] : -INFINITY;
    // strictly-unique 64-bit key: ascending K == (descending score, ascending index)
    unsigned ub   = __float_as_uint(s);
    unsigned mask = ((unsigned)((int)ub >> 31)) | 0x80000000u;
    unsigned ord  = ub ^ mask;          // ascending float order
    unsigned kd   = ~ord;               // descending float order
    key[i] = ((unsigned long long)kd << 32) | (unsigned)i;
    atomicAdd(&hist[kd >> 16], 1u);
}

// ---------------- K2: exclusive scan of 64K-bucket histogram -----------------
// Single block, 1024 threads, 64 buckets each.
__global__ void scan_kernel(const unsigned* __restrict__ hist,
                            unsigned* __restrict__ bstart,
                            unsigned* __restrict__ bcur) {
    __shared__ unsigned part[1024];
    const int t = threadIdx.x;
    const int base = t * 64;

    unsigned v[64];
    unsigned s = 0;
#pragma unroll
    for (int e = 0; e < 64; ++e) { v[e] = hist[base + e]; s += v[e]; }
    part[t] = s;
    __syncthreads();
    for (int off = 1; off < 1024; off <<= 1) {
        unsigned x = (t >= off) ? part[t - off] : 0u;
        __syncthreads();
        part[t] += x;
        __syncthreads();
    }
    unsigned run = (t == 0) ? 0u : part[t - 1];   // exclusive base for this chunk
#pragma unroll
    for (int e = 0; e < 64; ++e) {
        bstart[base + e] = run;
        bcur[base + e]   = run;
        run += v[e];
    }
}

// ---------------- K3: scatter keys into bucket-grouped array -----------------
__global__ void bucket_scatter_kernel(const unsigned long long* __restrict__ key,
                                      unsigned* __restrict__ bcur,
                                      unsigned long long* __restrict__ bkey) {
    int i = blockIdx.x * blockDim.x + threadIdx.x;
    if (i >= A_TOT) return;
    unsigned long long Ki = key[i];
    unsigned b = (unsigned)(Ki >> 48);
    unsigned pos = atomicAdd(&bcur[b], 1u);
    bkey[pos] = Ki;
}

// ---------------- K4: exact rank within bucket + scatter to sorted arrays ----
__global__ void rankscatter_kernel(const unsigned long long* __restrict__ key,
                                   const unsigned* __restrict__ hist,
                                   const unsigned* __restrict__ bstart,
                                   const unsigned long long* __restrict__ bkey,
                                   const float4* __restrict__ roi,
                                   float4* __restrict__ sboxes,
                                   float* __restrict__ sareas) {
    int i = blockIdx.x * blockDim.x + threadIdx.x;
    if (i >= A_TOT) return;
    unsigned long long Ki = key[i];
    unsigned b = (unsigned)(Ki >> 48);
    unsigned start = bstart[b];
    if (start >= N_PRE) return;            // rank >= start: not in top-N_PRE
    unsigned cnt = hist[b];
    unsigned r = start;
    if (cnt > 1) {
        for (unsigned m = 0; m < cnt; ++m)
            r += (bkey[start + m] < Ki) ? 1u : 0u;
    }
    if (r < N_PRE) {
        float4 bx = roi[i];
        sboxes[r] = bx;
        sareas[r] = __fmul_rn(__fadd_rn(__fsub_rn(bx.z, bx.x), 1.0f),
                              __fadd_rn(__fsub_rn(bx.w, bx.y), 1.0f));
    }
}

// ---------------- K5: diagonal pair-overlap marking --------------------------
// mark[i] = OR over z in [0, N_PRE-2-i] of IoU(b[z], b[z+i+1]) >= 0.7
__global__ void nms_kernel(const float4* __restrict__ sboxes,
                           const float* __restrict__ sareas,
                           unsigned* __restrict__ mark) {
    int wid  = (blockIdx.x * blockDim.x + threadIdx.x) >> 6;
    int lane = threadIdx.x & 63;
    if (wid >= N_PRE) return;
    const int i      = wid;
    const int npairs = N_PRE - 1 - i;   // z in [0, npairs)

    bool found = false;
    for (int base = 0; base < npairs; base += 64) {
        int z = base + lane;
        bool over = false;
        if (z < npairs) {
            float4 bz = sboxes[z];
            float4 bj = sboxes[z + i + 1];
            float az = sareas[z];
            float aj = sareas[z + i + 1];
            float xx1 = fmaxf(bz.x, bj.x);
            float yy1 = fmaxf(bz.y, bj.y);
            float xx2 = fminf(bz.z, bj.z);
            float yy2 = fminf(bz.w, bj.w);
            float w = fmaxf(0.0f, __fadd_rn(__fsub_rn(xx2, xx1), 1.0f));
            float h = fmaxf(0.0f, __fadd_rn(__fsub_rn(yy2, yy1), 1.0f));
            float inter = __fmul_rn(w, h);
            float denom = __fsub_rn(__fadd_rn(az, aj), inter);
            float ovr   = __fdiv_rn(inter, denom);
            over = (ovr >= NMS_T);
        }
        if (__any(over)) { found = true; break; }
    }
    if (lane == 0) mark[i] = found ? 1u : 0u;
}

// ---------------- K6: stable compaction + output -----------------------------
__global__ void output_kernel(const unsigned* __restrict__ mark,
                              const float4* __restrict__ sboxes,
                              float* __restrict__ out) {
    __shared__ int lds[1024];
    __shared__ int s_total;
    const int t = threadIdx.x;
    const int E = 12;                 // 1024*12 = 12288 >= 12000
    const int i0 = t * E;

    bool keep[E];
    int cnt = 0;
#pragma unroll
    for (int e = 0; e < E; ++e) {
        int i = i0 + e;
        bool k = (i < N_PRE) && (mark[i] == 0u);
        keep[e] = k;
        cnt += k ? 1 : 0;
    }
    lds[t] = cnt;
    __syncthreads();
    for (int off = 1; off < 1024; off <<= 1) {
        int x = (t >= off) ? lds[t - off] : 0;
        __syncthreads();
        lds[t] += x;
        __syncthreads();
    }
    int incl = lds[t];
    int base = incl - cnt;
    if (t == 1023) s_total = incl;
    __syncthreads();
    const int total = s_total;

    int pos = base;
#pragma unroll
    for (int e = 0; e < E; ++e) {
        if (keep[e] && pos < N_POST) {
            float4 b = sboxes[i0 + e];
            out[4*pos+0] = b.x;
            out[4*pos+1] = b.y;
            out[4*pos+2] = b.z;
            out[4*pos+3] = b.w;
            out[4*N_POST + pos] = 1.0f;
        }
        pos += keep[e] ? 1 : 0;
    }
    for (int p = t; p < N_POST; p += 1024) {
        if (p >= total) {
            out[4*p+0] = 0.0f; out[4*p+1] = 0.0f;
            out[4*p+2] = 0.0f; out[4*p+3] = 0.0f;
            out[4*N_POST + p] = 0.0f;
        }
    }
}

// ---------------- launch ------------------------------------------------------
extern "C" void kernel_launch(void* const* d_in, const int* in_sizes, int n_in,
                              void* d_out, int out_size, void* d_ws, size_t ws_size,
                              hipStream_t stream) {
    const float* anch = (const float*)d_in[0];   // (A,4)
    const float* cls  = (const float*)d_in[1];   // (1,A,2)
    const float* pred = (const float*)d_in[2];   // (1,A,4)
    float* out = (float*)d_out;                  // 8000 rois + 2000 kept

    char* ws = (char*)d_ws;
    float4*             roi    = (float4*)(ws + 0);        //   298,800
    unsigned long long* key    = (unsigned long long*)(ws + 299008);  // 149,400
    unsigned*           hist   = (unsigned*)(ws + 448512); // 262,144
    unsigned*           bstart = (unsigned*)(ws + 710656); // 262,144
    unsigned*           bcur   = (unsigned*)(ws + 972800); // 262,144
    unsigned long long* bkey   = (unsigned long long*)(ws + 1234944); // 149,400
    float4*             sboxes = (float4*)(ws + 1384448);  // 192,000
    float*              sareas = (float*)(ws + 1576448);   //  48,000
    unsigned*           mark   = (unsigned*)(ws + 1624448);//  48,000

    const int TB = 256;
    const int ablk = (A_TOT + TB - 1) / TB;      // 73

    hipMemsetAsync(hist, 0, NBUCK * sizeof(unsigned), stream);
    decode_kernel<<<ablk, TB, 0, stream>>>(anch, cls, pred, roi, key, hist);
    scan_kernel<<<1, 1024, 0, stream>>>(hist, bstart, bcur);
    bucket_scatter_kernel<<<ablk, TB, 0, stream>>>(key, bcur, bkey);
    rankscatter_kernel<<<ablk, TB, 0, stream>>>(key, hist, bstart, bkey, roi, sboxes, sareas);
    nms_kernel<<<(N_PRE * 64) / TB, TB, 0, stream>>>(sboxes, sareas, mark);
    output_kernel<<<1, 1024, 0, stream>>>(mark, sboxes, out);
}

// Round 4
// 72.374 us; speedup vs baseline: 1.0881x; 1.0881x over previous
//
#include <hip/hip_runtime.h>
#include <math.h>

#define A_TOT   18675      // 83*25*9
#define N_PRE   12000
#define N_POST  2000
#define IMG_X   1333.0f
#define IMG_Y   402.0f
#define MIN_SZ  16.0f
#define NMS_T   0.7f
#define NBUCK   65536

// ---------------- K0: zero the 64K-bucket histogram --------------------------
__global__ void zero_kernel(uint4* __restrict__ hist4) {
    int i = blockIdx.x * blockDim.x + threadIdx.x;   // 64*256 = 16384 uint4 = 65536 u32
    hist4[i] = make_uint4(0u, 0u, 0u, 0u);
}

// ---------------- K1: decode -> roi, key64, bucket histogram -----------------
__global__ void decode_kernel(const float* __restrict__ anch,
                              const float* __restrict__ cls,
                              const float* __restrict__ pred,
                              float4* __restrict__ roi,
                              unsigned long long* __restrict__ key,
                              unsigned* __restrict__ hist) {
    int i = blockIdx.x * blockDim.x + threadIdx.x;
    if (i >= A_TOT) return;

    float ax1 = anch[4*i+0], ay1 = anch[4*i+1], ax2 = anch[4*i+2], ay2 = anch[4*i+3];
    float h_a  = __fsub_rn(ay2, ay1);
    float w_a  = __fsub_rn(ax2, ax1);
    float cy_a = __fadd_rn(ay1, __fmul_rn(0.5f, h_a));
    float cx_a = __fadd_rn(ax1, __fmul_rn(0.5f, w_a));

    float dx = pred[4*i+0], dy = pred[4*i+1], dw = pred[4*i+2], dh = pred[4*i+3];

    float cy = __fadd_rn(__fmul_rn(dy, h_a), cy_a);
    float cx = __fadd_rn(__fmul_rn(dx, w_a), cx_a);
    float h  = __fmul_rn(expf(dh), h_a);
    float w  = __fmul_rn(expf(dw), w_a);

    float hw = __fmul_rn(0.5f, w);
    float hh = __fmul_rn(0.5f, h);
    float x1 = fminf(fmaxf(__fsub_rn(cx, hw), 0.0f), IMG_X);
    float x2 = fminf(fmaxf(__fadd_rn(cx, hw), 0.0f), IMG_X);
    float y1 = fminf(fmaxf(__fsub_rn(cy, hh), 0.0f), IMG_Y);
    float y2 = fminf(fmaxf(__fadd_rn(cy, hh), 0.0f), IMG_Y);

    bool valid = (__fsub_rn(y2, y1) >= MIN_SZ) && (__fsub_rn(x2, x1) >= MIN_SZ);

    roi[i] = make_float4(x1, y1, x2, y2);

    float s = valid ? cls[2*i+1] : -INFINITY;
    // strictly-unique 64-bit key: ascending K == (descending score, ascending index)
    unsigned ub   = __float_as_uint(s);
    unsigned mask = ((unsigned)((int)ub >> 31)) | 0x80000000u;
    unsigned ord  = ub ^ mask;          // ascending float order
    unsigned kd   = ~ord;               // descending float order
    key[i] = ((unsigned long long)kd << 32) | (unsigned)i;
    atomicAdd(&hist[kd >> 16], 1u);
}

// ---------------- K2: exclusive scan of 64K-bucket histogram -> bcur ---------
// Single block, 1024 threads, 64 buckets (16 uint4) each.
__global__ void scan_kernel(const uint4* __restrict__ hist4,
                            uint4* __restrict__ bcur4) {
    __shared__ unsigned part[1024];
    const int t = threadIdx.x;
    const int base = t * 16;            // uint4 index

    uint4 v[16];
    unsigned s = 0;
#pragma unroll
    for (int e = 0; e < 16; ++e) {
        v[e] = hist4[base + e];
        s += v[e].x + v[e].y + v[e].z + v[e].w;
    }
    part[t] = s;
    __syncthreads();
    for (int off = 1; off < 1024; off <<= 1) {
        unsigned x = (t >= off) ? part[t - off] : 0u;
        __syncthreads();
        part[t] += x;
        __syncthreads();
    }
    unsigned run = (t == 0) ? 0u : part[t - 1];   // exclusive base for this chunk
#pragma unroll
    for (int e = 0; e < 16; ++e) {
        uint4 o;
        o.x = run; run += v[e].x;
        o.y = run; run += v[e].y;
        o.z = run; run += v[e].z;
        o.w = run; run += v[e].w;
        bcur4[base + e] = o;
    }
}

// ---------------- K3: scatter keys into bucket-grouped array -----------------
__global__ void bucket_scatter_kernel(const unsigned long long* __restrict__ key,
                                      unsigned* __restrict__ bcur,
                                      unsigned long long* __restrict__ bkey) {
    int i = blockIdx.x * blockDim.x + threadIdx.x;
    if (i >= A_TOT) return;
    unsigned long long Ki = key[i];
    unsigned b = (unsigned)(Ki >> 48);
    unsigned pos = atomicAdd(&bcur[b], 1u);
    bkey[pos] = Ki;
}

// ---------------- K4: exact rank within bucket + scatter to sorted arrays ----
// After K3, bcur[b] = start[b] + cnt[b]; so start = bcur[b] - hist[b].
__global__ void rankscatter_kernel(const unsigned long long* __restrict__ key,
                                   const unsigned* __restrict__ hist,
                                   const unsigned* __restrict__ bcur,
                                   const unsigned long long* __restrict__ bkey,
                                   const float4* __restrict__ roi,
                                   float4* __restrict__ sboxes,
                                   float* __restrict__ sareas) {
    int i = blockIdx.x * blockDim.x + threadIdx.x;
    if (i >= A_TOT) return;
    unsigned long long Ki = key[i];
    unsigned b = (unsigned)(Ki >> 48);
    unsigned cnt   = hist[b];
    unsigned start = bcur[b] - cnt;
    if (start >= N_PRE) return;            // rank >= start: not in top-N_PRE
    unsigned r = start;
    if (cnt > 1) {
        for (unsigned m = 0; m < cnt; ++m)
            r += (bkey[start + m] < Ki) ? 1u : 0u;
    }
    if (r < N_PRE) {
        float4 bx = roi[i];
        sboxes[r] = bx;
        sareas[r] = __fmul_rn(__fadd_rn(__fsub_rn(bx.z, bx.x), 1.0f),
                              __fadd_rn(__fsub_rn(bx.w, bx.y), 1.0f));
    }
}

// ---------------- K5: diagonal pair-overlap marking --------------------------
// mark[i] = OR over z in [0, N_PRE-2-i] of IoU(b[z], b[z+i+1]) >= 0.7
__global__ void nms_kernel(const float4* __restrict__ sboxes,
                           const float* __restrict__ sareas,
                           unsigned* __restrict__ mark) {
    int wid  = (blockIdx.x * blockDim.x + threadIdx.x) >> 6;
    int lane = threadIdx.x & 63;
    if (wid >= N_PRE) return;
    const int i      = wid;
    const int npairs = N_PRE - 1 - i;   // z in [0, npairs)

    bool found = false;
    for (int base = 0; base < npairs; base += 64) {
        int z = base + lane;
        bool over = false;
        if (z < npairs) {
            float4 bz = sboxes[z];
            float4 bj = sboxes[z + i + 1];
            float az = sareas[z];
            float aj = sareas[z + i + 1];
            float xx1 = fmaxf(bz.x, bj.x);
            float yy1 = fmaxf(bz.y, bj.y);
            float xx2 = fminf(bz.z, bj.z);
            float yy2 = fminf(bz.w, bj.w);
            float w = fmaxf(0.0f, __fadd_rn(__fsub_rn(xx2, xx1), 1.0f));
            float h = fmaxf(0.0f, __fadd_rn(__fsub_rn(yy2, yy1), 1.0f));
            float inter = __fmul_rn(w, h);
            float denom = __fsub_rn(__fadd_rn(az, aj), inter);
            float ovr   = __fdiv_rn(inter, denom);
            over = (ovr >= NMS_T);
        }
        if (__any(over)) { found = true; break; }
    }
    if (lane == 0) mark[i] = found ? 1u : 0u;
}

// ---------------- K6: stable compaction + output -----------------------------
__global__ void output_kernel(const unsigned* __restrict__ mark,
                              const float4* __restrict__ sboxes,
                              float* __restrict__ out) {
    __shared__ int lds[1024];
    __shared__ int s_total;
    const int t = threadIdx.x;
    const int E = 12;                 // 1024*12 = 12288 >= 12000
    const int i0 = t * E;

    bool keep[E];
    int cnt = 0;
#pragma unroll
    for (int e = 0; e < E; ++e) {
        int i = i0 + e;
        bool k = (i < N_PRE) && (mark[i] == 0u);
        keep[e] = k;
        cnt += k ? 1 : 0;
    }
    lds[t] = cnt;
    __syncthreads();
    for (int off = 1; off < 1024; off <<= 1) {
        int x = (t >= off) ? lds[t - off] : 0;
        __syncthreads();
        lds[t] += x;
        __syncthreads();
    }
    int incl = lds[t];
    int base = incl - cnt;
    if (t == 1023) s_total = incl;
    __syncthreads();
    const int total = s_total;

    int pos = base;
#pragma unroll
    for (int e = 0; e < E; ++e) {
        if (keep[e] && pos < N_POST) {
            float4 b = sboxes[i0 + e];
            out[4*pos+0] = b.x;
            out[4*pos+1] = b.y;
            out[4*pos+2] = b.z;
            out[4*pos+3] = b.w;
            out[4*N_POST + pos] = 1.0f;
        }
        pos += keep[e] ? 1 : 0;
    }
    for (int p = t; p < N_POST; p += 1024) {
        if (p >= total) {
            out[4*p+0] = 0.0f; out[4*p+1] = 0.0f;
            out[4*p+2] = 0.0f; out[4*p+3] = 0.0f;
            out[4*N_POST + p] = 0.0f;
        }
    }
}

// ---------------- launch ------------------------------------------------------
extern "C" void kernel_launch(void* const* d_in, const int* in_sizes, int n_in,
                              void* d_out, int out_size, void* d_ws, size_t ws_size,
                              hipStream_t stream) {
    const float* anch = (const float*)d_in[0];   // (A,4)
    const float* cls  = (const float*)d_in[1];   // (1,A,2)
    const float* pred = (const float*)d_in[2];   // (1,A,4)
    float* out = (float*)d_out;                  // 8000 rois + 2000 kept

    char* ws = (char*)d_ws;
    float4*             roi    = (float4*)(ws + 0);                   // 298,800
    unsigned long long* key    = (unsigned long long*)(ws + 299008);  // 149,400
    unsigned*           hist   = (unsigned*)(ws + 448512);            // 262,144
    unsigned*           bcur   = (unsigned*)(ws + 710656);            // 262,144
    unsigned long long* bkey   = (unsigned long long*)(ws + 972800);  // 149,400
    float4*             sboxes = (float4*)(ws + 1122304);             // 192,000
    float*              sareas = (float*)(ws + 1314304);              //  48,000
    unsigned*           mark   = (unsigned*)(ws + 1362304);           //  48,000

    const int TB = 256;
    const int ablk = (A_TOT + TB - 1) / TB;      // 73

    zero_kernel<<<64, TB, 0, stream>>>((uint4*)hist);
    decode_kernel<<<ablk, TB, 0, stream>>>(anch, cls, pred, roi, key, hist);
    scan_kernel<<<1, 1024, 0, stream>>>((const uint4*)hist, (uint4*)bcur);
    bucket_scatter_kernel<<<ablk, TB, 0, stream>>>(key, bcur, bkey);
    rankscatter_kernel<<<ablk, TB, 0, stream>>>(key, hist, bcur, bkey, roi, sboxes, sareas);
    nms_kernel<<<(N_PRE * 64) / TB, TB, 0, stream>>>(sboxes, sareas, mark);
    output_kernel<<<1, 1024, 0, stream>>>(mark, sboxes, out);
}